// Round 2
// baseline (143.308 us; speedup 1.0000x reference)
//
#include <hip/hip_runtime.h>
#include <stdint.h>

#define GRAPHS 256
#define NPG    512
#define EPG    8192
#define NTOT   (GRAPHS*NPG)

typedef __attribute__((ext_vector_type(8))) short s16x8;
typedef __attribute__((ext_vector_type(4))) float f32x4;

__device__ __forceinline__ float bf2f(unsigned short u){
  union { unsigned int i; float f; } c; c.i = ((unsigned int)u)<<16; return c.f;
}
__device__ __forceinline__ unsigned short f2bf(float f){
  union { float f; unsigned int i; } c; c.f = f;
  unsigned int r = c.i + 0x7fffu + ((c.i>>16)&1u);   // RNE
  return (unsigned short)(r>>16);
}
// packed f32x2 -> bf16x2, SOFTWARE RNE (v_cvt_pk_bf16_f32 is not bit-identical
// to RNE f2bf -> caused 3.7e-3 absmax fail in R1; do NOT use the asm form)
__device__ __forceinline__ unsigned int cvt_pk_bf16(float a, float b){
  return (unsigned int)f2bf(a) | ((unsigned int)f2bf(b)<<16);
}

// ---------- CSR build + out_isqrt + folded prep (grid = 256, no tail) -------
// prep folded into each block's tail: 32 EW1T items, 64 W2F items, 32 out-zero
//   EW1T (emb@W1)^T bf16; W2F = W2 in MFMA-B-fragment order:
//   W2F[((ks*8+nt)*64+lane)*8+j] = bf16(W2[ks*32+(lane>>4)*8+j][nt*16+(lane&15)])
__global__ __launch_bounds__(512) void k_csr(const int* __restrict__ src,
      const int* __restrict__ dst, const int* __restrict__ ntype,
      const float* __restrict__ emb, const float* __restrict__ W1,
      const float* __restrict__ W2,
      unsigned int* __restrict__ sorted_g, int* __restrict__ start_g,
      float* __restrict__ out_isqrt, unsigned short* __restrict__ EW1T,
      unsigned short* __restrict__ W2F, float* __restrict__ outz){
  __shared__ int hist[NPG], cursor[NPG], co[NPG], cs[NPG+1];
  __shared__ unsigned short ntype_sh[NPG];
  __shared__ unsigned int sorted[EPG];
  const int tid=threadIdx.x;
  const int b=blockIdx.x, eb=b*EPG, nb=b*NPG;
  hist[tid]=0; co[tid]=0; ntype_sh[tid]=(unsigned short)ntype[nb+tid];
  __syncthreads();
  int4 d4[4], s4[4];
  {
    const int4* dv = (const int4*)(dst+eb);
    const int4* sv = (const int4*)(src+eb);
    #pragma unroll
    for (int j=0;j<4;j++){
      d4[j]=dv[tid + j*512];
      s4[j]=sv[tid + j*512];
      atomicAdd(&hist[d4[j].x&(NPG-1)],1); atomicAdd(&hist[d4[j].y&(NPG-1)],1);
      atomicAdd(&hist[d4[j].z&(NPG-1)],1); atomicAdd(&hist[d4[j].w&(NPG-1)],1);
      atomicAdd(&co[s4[j].x&(NPG-1)],1);   atomicAdd(&co[s4[j].y&(NPG-1)],1);
      atomicAdd(&co[s4[j].z&(NPG-1)],1);   atomicAdd(&co[s4[j].w&(NPG-1)],1);
    }
  }
  __syncthreads();
  if (tid<64){
    int carry=0;
    #pragma unroll
    for (int c=0;c<8;c++){
      int sc=hist[64*c+tid];
      #pragma unroll
      for (int off=1;off<64;off<<=1){ int y=__shfl_up(sc,off); if (tid>=off) sc+=y; }
      cs[64*c+tid+1]=carry+sc;
      carry+=__shfl(sc,63);
    }
    if (tid==0) cs[0]=0;
  }
  __syncthreads();
  cursor[tid]=cs[tid];
  __syncthreads();
  #pragma unroll
  for (int j=0;j<4;j++){
    int dl, s, pos;
    dl=d4[j].x&(NPG-1); s=s4[j].x&(NPG-1);
    pos=atomicAdd(&cursor[dl],1);
    sorted[pos]=((unsigned int)dl<<15)|((unsigned int)ntype_sh[s]<<9)|(unsigned int)s;
    dl=d4[j].y&(NPG-1); s=s4[j].y&(NPG-1);
    pos=atomicAdd(&cursor[dl],1);
    sorted[pos]=((unsigned int)dl<<15)|((unsigned int)ntype_sh[s]<<9)|(unsigned int)s;
    dl=d4[j].z&(NPG-1); s=s4[j].z&(NPG-1);
    pos=atomicAdd(&cursor[dl],1);
    sorted[pos]=((unsigned int)dl<<15)|((unsigned int)ntype_sh[s]<<9)|(unsigned int)s;
    dl=d4[j].w&(NPG-1); s=s4[j].w&(NPG-1);
    pos=atomicAdd(&cursor[dl],1);
    sorted[pos]=((unsigned int)dl<<15)|((unsigned int)ntype_sh[s]<<9)|(unsigned int)s;
  }
  __syncthreads();
  for (int i=tid;i<EPG;i+=512) sorted_g[(size_t)eb+i] = sorted[i];
  if (tid==0) start_g[b*(NPG+1)+NPG]=cs[NPG];
  start_g[b*(NPG+1)+tid]=cs[tid];
  {
    int a=co[tid]; if(a<1)a=1;
    out_isqrt[nb+tid]=rsqrtf((float)a);
  }
  // ---- folded prep (independent global work; no sync needed) ----
  if (tid < 32){                                 // EW1T: 32 items/block (wave 0)
    const int gid = b*32 + tid;
    const int t = gid>>7, c = gid&127;
    float acc=0.f;
    #pragma unroll 4
    for (int k=0;k<128;k++) acc += emb[t*128+k]*W1[k*128+c];
    EW1T[c*64+t]=f2bf(acc);
  } else if (tid >= 64 && tid < 128){            // W2F: 64 items/block (wave 1)
    const int i = b*64 + (tid-64);
    const int ks = i>>12, nt=(i>>9)&7, ln=(i>>3)&63, j=i&7;
    const int k = ks*32 + (ln>>4)*8 + j;
    const int n = nt*16 + (ln&15);
    W2F[i] = f2bf(W2[k*128+n]);
  } else if (tid >= 128 && tid < 160){           // zero d_out: 32 f32x4/block
    ((f32x4*)outz)[b*32 + (tid-128)] = (f32x4){0.f,0.f,0.f,0.f};
  }
}

// ---------- layer-1 + H2: S-hist + MFMA(S@EW1) -> h1(LDS) -> MFMA(h1@W2F) ---
// block = (graph, half: 256 dst rows), 512 thr, 75 KB LDS (2 blocks/CU).
// Pass 1: fixed-point edge-parallel S; hi/lo bf16 A-frags built ONCE;
//         each EW1T B-frag loaded once, feeds hi AND lo MFMAs.
// Pass 2: H2 = h1 @ W2 (A-frags from LDS, B-frags coalesced from global W2F),
//         H2F written in agg2-B-fragment order (R13 layout).
#define A1_LDS 75280   // Sint[256][68]/h1sh[256][136] | wsc | wint | sstart | bsh
__global__ __launch_bounds__(512) void k_agg1(
      const unsigned int* __restrict__ sorted_g, const int* __restrict__ start_g,
      const unsigned short* __restrict__ EW1T, const float* __restrict__ out_isqrt,
      const float* __restrict__ b1, const unsigned short* __restrict__ W2F,
      unsigned short* __restrict__ H2F){
  extern __shared__ char smem[];
  int*   Sint   = (int*)(smem);                 // [256][68]  (pass 1)
  unsigned short* h1sh = (unsigned short*)(smem); // [256][136] (pass 2 alias)
  float* wsc    = (float*)(smem + 69632);       // [512]
  int*   wint   = (int*)  (smem + 71680);       // [512]
  int*   sstart = (int*)  (smem + 73728);       // [257]
  float* bsh    = (float*)(smem + 74756);       // [128]
  const int bid=blockIdx.x;
  const int b    = ((bid>>4)<<3) | (bid&7);     // graph (XCD-aligned swizzle)
  const int half = (bid>>3)&1;
  const int v0=half*256, nb=b*NPG, tid=threadIdx.x;
  for (int i=tid; i<(256*68)/4; i+=512) ((f32x4*)Sint)[i]=(f32x4){0.f,0.f,0.f,0.f};
  for (int i=tid; i<NPG; i+=512){
    const float w = out_isqrt[nb+i];
    wsc[i]=w;
    wint[i]=(int)(w*1048576.f);                 // 2^20 fixed point
  }
  for (int i=tid; i<257; i+=512) sstart[i]=start_g[b*(NPG+1)+v0+i];
  if (tid<128) bsh[tid]=b1[tid];
  __syncthreads();
  {                                             // edge-parallel int scatter
    const int beg=sstart[0], end=sstart[256];
    const unsigned int* sg = sorted_g + (size_t)b*EPG;
    for (int i=beg+tid; i<end; i+=512){
      const unsigned int ent = sg[i];
      const int dl = (int)(ent>>15) - v0;       // in [0,256)
      const int t  = (ent>>9)&63;
      atomicAdd(&Sint[dl*68 + t], wint[ent&511]);
    }
  }
  __syncthreads();
  const int wave=tid>>6, lane=tid&63, l16=lane&15, quad=lane>>4;
  f32x4 acc[2][8];
  #pragma unroll
  for (int rt=0;rt<2;rt++)
    #pragma unroll
    for (int nt=0;nt<8;nt++) acc[rt][nt]=(f32x4){0.f,0.f,0.f,0.f};
  #pragma unroll
  for (int kh=0; kh<2; ++kh){                   // K-half: cols kh*32+quad*8
    s16x8 fh[2], fl[2];                         // hi/lo frags, built once
    #pragma unroll
    for (int rt=0;rt<2;rt++){
      const int m = (wave*2+rt)*16 + l16;
      const int* sp = &Sint[m*68 + kh*32 + quad*8];
      union { s16x8 v; unsigned int u[4]; } hv, lv;
      #pragma unroll
      for (int p=0;p<4;p++){
        const float f0 = (float)sp[2*p]   * (1.f/1048576.f);  // exact exp shift
        const float f1 = (float)sp[2*p+1] * (1.f/1048576.f);
        const unsigned int h = cvt_pk_bf16(f0, f1);
        hv.u[p] = h;
        const float r0 = f0 - __builtin_bit_cast(float, h<<16);
        const float r1 = f1 - __builtin_bit_cast(float, h & 0xffff0000u);
        lv.u[p] = cvt_pk_bf16(r0, r1);
      }
      fh[rt]=hv.v; fl[rt]=lv.v;
    }
    const int kc = kh*32 + quad*8;
    #pragma unroll
    for (int nt=0;nt<8;nt++){                   // one B-frag feeds hi AND lo
      s16x8 bfr=__builtin_bit_cast(s16x8,
          *(const uint4*)(EW1T + (size_t)(nt*16+l16)*64 + kc));
      acc[0][nt]=__builtin_amdgcn_mfma_f32_16x16x32_bf16(fh[0],bfr,acc[0][nt],0,0,0);
      acc[1][nt]=__builtin_amdgcn_mfma_f32_16x16x32_bf16(fh[1],bfr,acc[1][nt],0,0,0);
      acc[0][nt]=__builtin_amdgcn_mfma_f32_16x16x32_bf16(fl[0],bfr,acc[0][nt],0,0,0);
      acc[1][nt]=__builtin_amdgcn_mfma_f32_16x16x32_bf16(fl[1],bfr,acc[1][nt],0,0,0);
    }
  }
  // ---- epilogue 1: h1 = relu(agg*isq+b1)*osc -> LDS (C-layout) ----
  float isq[2][4], os[2][4];
  #pragma unroll
  for (int rt=0;rt<2;rt++){
    const int mloc = (wave*2+rt)*16 + quad*4;
    #pragma unroll
    for (int r=0;r<4;r++){
      int d = sstart[mloc+r+1]-sstart[mloc+r]; if (d<1) d=1;
      isq[rt][r]=rsqrtf((float)d);
      os[rt][r]=wsc[v0+mloc+r];
    }
  }
  __syncthreads();                              // all Sint reads done
  #pragma unroll
  for (int rt=0;rt<2;rt++){
    const int mloc = (wave*2+rt)*16 + quad*4;
    #pragma unroll
    for (int nt=0;nt<8;nt++){
      const int col = nt*16+l16;
      const float bb = bsh[col];
      #pragma unroll
      for (int r=0;r<4;r++){
        const float v = fmaxf(acc[rt][nt][r]*isq[rt][r]+bb,0.f)*os[rt][r];
        h1sh[(mloc+r)*136 + col] = f2bf(v);
      }
    }
  }
  __syncthreads();
  // ---- pass 2: H2 = h1 @ W2 (K=128), B from global W2F (coalesced) ----
  f32x4 acc2[2][8];
  #pragma unroll
  for (int rt=0;rt<2;rt++)
    #pragma unroll
    for (int nt=0;nt<8;nt++) acc2[rt][nt]=(f32x4){0.f,0.f,0.f,0.f};
  #pragma unroll
  for (int ks=0; ks<4; ++ks){
    s16x8 a2[2];
    #pragma unroll
    for (int rt=0;rt<2;rt++){
      const int m = (wave*2+rt)*16 + l16;
      a2[rt]=__builtin_bit_cast(s16x8,
          *(const uint4*)(h1sh + m*136 + ks*32 + quad*8));
    }
    #pragma unroll
    for (int nt=0;nt<8;nt++){
      s16x8 bfr=__builtin_bit_cast(s16x8,
          *(const uint4*)(W2F + (size_t)(((ks*8+nt)*64)+lane)*8));
      #pragma unroll
      for (int rt=0;rt<2;rt++)
        acc2[rt][nt]=__builtin_amdgcn_mfma_f32_16x16x32_bf16(a2[rt],bfr,acc2[rt][nt],0,0,0);
    }
  }
  // ---- epilogue 2: H2F in agg2-B-fragment order (R13 remap) ----
  #pragma unroll
  for (int rt=0;rt<2;rt++){
    const int W = wave*2+rt;
    const int ks2 = half*8 + (W>>1);
    const int q2  = ((W&1)<<1) | (quad>>1);
    const int j0  = (quad&1)*4;
    #pragma unroll
    for (int nt=0;nt<8;nt++){
      ushort4 st;
      st.x=f2bf(acc2[rt][nt][0]); st.y=f2bf(acc2[rt][nt][1]);
      st.z=f2bf(acc2[rt][nt][2]); st.w=f2bf(acc2[rt][nt][3]);
      const size_t off = ((((size_t)b*16 + ks2)*8 + nt)*64 + q2*16 + l16)*8 + j0;
      *(ushort4*)(H2F + off) = st;
    }
  }
}

// ---------- layer-2: counts @ H2F, epilogue relu(acc*isq+b2) colsum ---------
// block = (graph, 128-dst tile). Wave map (|mset|=4,|nset|=2): each B-frag
// read by 2 waves (was 4) -> H2F L2 traffic halved; A unpack via
// float-cast + v_perm_b32 packing (exact for small ints). k_final folded:
// atomicAdd into out (out zeroed by k_csr tail).
#define A2_LDS 67592   // A u8[128][520] (red[8][32] alias) | sstart[129] | bsh[128]
__global__ __launch_bounds__(512) void k_agg2(
      const unsigned int* __restrict__ sorted_g, const int* __restrict__ start_g,
      const unsigned short* __restrict__ H2F, const float* __restrict__ b2,
      float* __restrict__ out){
  extern __shared__ char smem[];
  unsigned char* A = (unsigned char*)smem;      // [128][520]
  unsigned int* A32 = (unsigned int*)smem;
  float* red = (float*)smem;                    // [8][32] (alias, post-MFMA)
  int* sstart = (int*)(smem + 66560);           // [129]
  float* bsh  = (float*)(smem + 67080);         // [128]
  const int bid=blockIdx.x;
  const int b  = ((bid>>5)<<3) | (bid&7);       // graph (XCD swizzle)
  const int dt = (bid>>3)&3;                    // dst tile
  const int v0=dt*128, tid=threadIdx.x;
  for (int i=tid; i<66560/16; i+=512) ((uint4*)smem)[i]=(uint4){0u,0u,0u,0u};
  for (int i=tid; i<129; i+=512) sstart[i]=start_g[b*(NPG+1)+v0+i];
  if (tid<128) bsh[tid]=b2[tid];
  __syncthreads();
  {                                             // edge-parallel count scatter
    const int beg=sstart[0], end=sstart[128];
    const unsigned int* sg = sorted_g + (size_t)b*EPG;
    for (int i=beg+tid; i<end; i+=512){
      const unsigned int ent = sg[i];
      const int dl = (int)(ent>>15) - v0;       // in [0,128)
      const int s  = ent&511;
      atomicAdd(&A32[dl*130 + (s>>2)], 1u<<((s&3)*8));
    }
  }
  __syncthreads();
  const int wave=tid>>6, lane=tid&63, l16=lane&15, quad=lane>>4;
  const int mg=wave>>2, ng=wave&3;              // 2 m-groups x 4 n-groups
  f32x4 acc[4][2];
  #pragma unroll
  for (int rt=0;rt<4;rt++)
    #pragma unroll
    for (int ct=0;ct<2;ct++) acc[rt][ct]=(f32x4){0.f,0.f,0.f,0.f};
  const uint4* bp[2];                           // coalesced fragment pointers
  #pragma unroll
  for (int ct=0;ct<2;ct++)
    bp[ct] = (const uint4*)H2F + (((size_t)b*16)*8 + (ng*2+ct))*64 + lane;
  const unsigned char* Ab[4];
  #pragma unroll
  for (int rt=0;rt<4;rt++)
    Ab[rt] = A + ((mg*4+rt)*16 + l16)*520 + quad*8;
  #pragma unroll 2
  for (int ks=0; ks<16; ++ks){
    const uint4 bq0 = bp[0][(size_t)ks*512];
    const uint4 bq1 = bp[1][(size_t)ks*512];
    #pragma unroll
    for (int rt=0;rt<4;rt++){
      const uint2 aw = *(const uint2*)(Ab[rt] + ks*32);
      union { s16x8 v; unsigned int u[4]; } pk;
      {                                         // exact small ints -> bf16
        const float g0=(float)( aw.x       &0xffu);
        const float g1=(float)((aw.x>> 8u) &0xffu);
        const float g2=(float)((aw.x>>16u) &0xffu);
        const float g3=(float)( aw.x>>24u        );
        pk.u[0]=__builtin_amdgcn_perm(__builtin_bit_cast(unsigned int,g1),
                                      __builtin_bit_cast(unsigned int,g0),0x07060302u);
        pk.u[1]=__builtin_amdgcn_perm(__builtin_bit_cast(unsigned int,g3),
                                      __builtin_bit_cast(unsigned int,g2),0x07060302u);
      }
      {
        const float g0=(float)( aw.y       &0xffu);
        const float g1=(float)((aw.y>> 8u) &0xffu);
        const float g2=(float)((aw.y>>16u) &0xffu);
        const float g3=(float)( aw.y>>24u        );
        pk.u[2]=__builtin_amdgcn_perm(__builtin_bit_cast(unsigned int,g1),
                                      __builtin_bit_cast(unsigned int,g0),0x07060302u);
        pk.u[3]=__builtin_amdgcn_perm(__builtin_bit_cast(unsigned int,g3),
                                      __builtin_bit_cast(unsigned int,g2),0x07060302u);
      }
      acc[rt][0]=__builtin_amdgcn_mfma_f32_16x16x32_bf16(pk.v,
          __builtin_bit_cast(s16x8, bq0), acc[rt][0],0,0,0);
      acc[rt][1]=__builtin_amdgcn_mfma_f32_16x16x32_bf16(pk.v,
          __builtin_bit_cast(s16x8, bq1), acc[rt][1],0,0,0);
    }
  }
  // epilogue: relu(acc*isq + b2), column sums, atomicAdd into out (k_final fold)
  float p[2]; p[0]=0.f; p[1]=0.f;
  #pragma unroll
  for (int rt=0;rt<4;rt++){
    const int mloc=(mg*4+rt)*16 + quad*4;
    float isq[4];
    #pragma unroll
    for (int r=0;r<4;r++){
      int d=sstart[mloc+r+1]-sstart[mloc+r]; if (d<1) d=1;
      isq[r]=rsqrtf((float)d);
    }
    #pragma unroll
    for (int ct=0;ct<2;ct++){
      const int col=ng*32 + ct*16 + l16;
      const float bb = bsh[col];
      #pragma unroll
      for (int r=0;r<4;r++)
        p[ct] += fmaxf(acc[rt][ct][r]*isq[r]+bb,0.f);
    }
  }
  #pragma unroll
  for (int ct=0;ct<2;ct++){
    p[ct] += __shfl_xor(p[ct],16);              // reduce across quad (rows)
    p[ct] += __shfl_xor(p[ct],32);
  }
  __syncthreads();                              // all A reads done; red aliases A
  if (quad==0){
    red[wave*32 + l16]      = p[0];
    red[wave*32 + 16 + l16] = p[1];
  }
  __syncthreads();
  if (tid<128){
    const int col=tid, ngc=col>>5, c5=col&31;
    const float s = red[ngc*32 + c5] + red[(4+ngc)*32 + c5];   // mg=0, mg=1
    atomicAdd(out + (size_t)b*128 + col, s*(1.f/512.f));
  }
}

extern "C" void kernel_launch(void* const* d_in, const int* in_sizes, int n_in,
                              void* d_out, int out_size, void* d_ws, size_t ws_size,
                              hipStream_t stream){
  const int* node_feat = (const int*)d_in[0];
  const int* src = (const int*)d_in[1];
  const int* dst = (const int*)d_in[2];
  const float* emb = (const float*)d_in[3];
  const float* W1  = (const float*)d_in[4];
  const float* b1  = (const float*)d_in[5];
  const float* W2  = (const float*)d_in[6];
  const float* b2  = (const float*)d_in[7];

  char* ws = (char*)d_ws;
  float* out_isqrt        = (float*)(ws);                          // 524288 B
  int* start_g            = (int*)(ws + 524288);                   // 525312 B
  unsigned int* sorted_g  = (unsigned int*)(ws + 1049600);         // 8388608 B
  unsigned short* EW1T    = (unsigned short*)(ws + 9438208);       // 16384 B
  unsigned short* W2F     = (unsigned short*)(ws + 9454592);       // 32768 B
  unsigned short* H2F     = (unsigned short*)(ws + 9487360);       // 33554432 B

  (void)hipFuncSetAttribute(reinterpret_cast<const void*>(&k_agg1),
        hipFuncAttributeMaxDynamicSharedMemorySize, A1_LDS);
  (void)hipFuncSetAttribute(reinterpret_cast<const void*>(&k_agg2),
        hipFuncAttributeMaxDynamicSharedMemorySize, A2_LDS);

  k_csr<<<GRAPHS,512,0,stream>>>(src,dst,node_feat,emb,W1,W2,
        sorted_g,start_g,out_isqrt,EW1T,W2F,(float*)d_out);
  k_agg1<<<GRAPHS*2,512,A1_LDS,stream>>>(sorted_g,start_g,EW1T,out_isqrt,b1,
        W2F,H2F);
  k_agg2<<<GRAPHS*4,512,A2_LDS,stream>>>(sorted_g,start_g,H2F,b2,(float*)d_out);
}